// Round 1
// baseline (446.402 us; speedup 1.0000x reference)
//
#include <hip/hip_runtime.h>
#include <hip/hip_bf16.h>
#include <stdint.h>
#include <stddef.h>

// Problem dims (fixed): B=64, C=128, H=W=56, 3x3 conv pad=1 stride=1.
#define CH 128
#define HH 56
#define WW 56
#define HWPIX (HH*WW)        // 3136
#define NB 64
#define NPIXF 200704.0f      // B*H*W
#define NCONVBLK 3136        // 64 samples x 49 tiles (8x8 px)

typedef __attribute__((ext_vector_type(8))) short short8v;    // 8 bf16 -> MFMA A/B frag
typedef __attribute__((ext_vector_type(8))) unsigned short bfv8;
typedef __attribute__((ext_vector_type(4))) unsigned short bfv4;
typedef __attribute__((ext_vector_type(4))) float f32x4;

__device__ __forceinline__ unsigned short f2bf(float f) {
  unsigned int u = __float_as_uint(f);
  u += 0x7fffu + ((u >> 16) & 1u);            // RNE
  return (unsigned short)(u >> 16);
}
__device__ __forceinline__ float bf2f(unsigned short s) {
  return __uint_as_float(((unsigned int)s) << 16);
}

// ---------------------------------------------------------------------------
// K1: x NCHW fp32 -> NHWC bf16 (LDS transpose, coalesced 16B/lane writes).
__global__ __launch_bounds__(256)
void prep_x(const float* __restrict__ x, unsigned short* __restrict__ xT) {
  __shared__ unsigned short tile[4 * 56 * 128];
  const int bid = blockIdx.x;
  const int b = bid / 14, hq = bid % 14;
  const int hl = threadIdx.x >> 6;
  const int h = hq * 4 + hl;
  const int w = threadIdx.x & 63;
  if (w < WW) {
    const float* src = x + (size_t)b * CH * HWPIX + h * WW + w;
    const int pos = hl * WW + w;
    #pragma unroll 4
    for (int c0 = 0; c0 < CH; c0 += 8) {
      bfv8 v;
      #pragma unroll
      for (int k = 0; k < 8; ++k) v[k] = f2bf(src[(size_t)(c0 + k) * HWPIX]);
      const int idx = (pos * CH + c0) ^ ((pos & 7) << 3);
      *(bfv8*)(tile + idx) = v;
    }
  }
  __syncthreads();
  unsigned short* out = xT + (size_t)(b * HH + hq * 4) * WW * CH;
  #pragma unroll
  for (int j = 0; j < 14; ++j) {
    const int u = j * 256 + threadIdx.x;
    const int idx = (u * 8) ^ (((u >> 4) & 7) << 3);
    *(bfv8*)(out + u * 8) = *(const bfv8*)(tile + idx);
  }
}

// ---------------------------------------------------------------------------
// K2: weights [B,O,I,3,3] fp32 -> [B,tap,O,I] bf16 (dense reads, 16B writes).
__global__ __launch_bounds__(256)
void prep_w(const float* __restrict__ w1, const float* __restrict__ w2,
            unsigned short* __restrict__ o1, unsigned short* __restrict__ o2) {
  __shared__ unsigned short lw[18432];
  const int id = blockIdx.x;
  const int which = id >> 9;
  const int b = (id >> 3) & 63, ck = id & 7;
  const float* src = (which ? w2 : w1) + ((size_t)b * 16384 + ck * 2048) * 9;
  unsigned short* dst = (which ? o2 : o1);
  const int t = threadIdx.x;
  #pragma unroll
  for (int j = 0; j < 72; ++j)
    lw[j * 256 + t] = f2bf(src[j * 256 + t]);
  __syncthreads();
  const int ol = t >> 4, oct = t & 15;
  #pragma unroll
  for (int tap = 0; tap < 9; ++tap) {
    bfv8 v;
    #pragma unroll
    for (int k = 0; k < 8; ++k) v[k] = lw[(ol * 128 + oct * 8 + k) * 9 + tap];
    *(bfv8*)(dst + ((size_t)(b * 9 + tap) * CH + ck * 16 + ol) * CH + oct * 8) = v;
  }
}

// ---------------------------------------------------------------------------
// K3/K5: per-sample conv, implicit GEMM.
// R9: drop the weight rotation from 4 buffers (depth-2, 64 VGPR) to 2 buffers
// (depth-1, 32 VGPR). Theory: combined VGPR+AGPR was ~148-180 -> only 2-3
// waves/SIMD resident (Occupancy 21%); freeing 32 regs gets combined <=128 ->
// 4 waves/SIMD. Depth-1 lookahead (~1 stage ~110cyc issue) x 4 co-resident
// waves covers the ~200-400cyc L2 weight-load latency that depth-2 covered
// per-wave. Everything else is the R6/R8 structure verbatim (spill is fatal:
// cap ~= 256/N for launch_bounds(256,N)).
template<bool FUSE>
__global__ __launch_bounds__(256, 2)
void conv_kernel(const unsigned short* __restrict__ in,
                 const unsigned short* __restrict__ wt,
                 unsigned short* __restrict__ outp,
                 float* __restrict__ partials,
                 const float* __restrict__ tab) {   // [256]: scale | shift (FUSE)
  __shared__ unsigned short patch[100 * 136];
  __shared__ float sacc[256];                       // sum[128] | sumsq[128]
  const int xcd = blockIdx.x & 7;
  const int q = blockIdx.x >> 3;                    // 0..391
  const int s = q / 49;
  const int tile = q - s * 49;
  const int b = s * 8 + xcd;
  const int ty = tile / 7, tx = tile % 7;
  const int h0 = ty * 8, w0 = tx * 8;
  const int t = threadIdx.x;

  const int lane = t & 63, wv = t >> 6;
  const int lrow = lane & 15, lgrp = lane >> 4;
  const int px = lrow & 7, pyl = lrow >> 3;

  sacc[t] = 0.0f;

  // A: lane holds W[o = wv*32 + mf*16 + lrow][k]; half I covers k-chunk
  // (I%2)*64 + {0,32} for rows lrow and lrow+16.
  const unsigned short* wbase =
      wt + (size_t)b * 9 * CH * CH + (wv * 32 + lrow) * CH + lgrp * 8;

  short8v b0[4], b1[4];
#define LOAD_HALF(dst, I) { \
    const unsigned short* wtap_ = wbase + ((I) / 2) * CH * CH + ((I) % 2) * 64; \
    _Pragma("unroll") \
    for (int c2 = 0; c2 < 2; ++c2) { \
      dst[c2 * 2 + 0] = *(const short8v*)(wtap_ + c2 * 32); \
      dst[c2 * 2 + 1] = *(const short8v*)(wtap_ + 16 * CH + c2 * 32); \
    } }

  // Head start: first two halves in flight before/through the staging barrier.
  LOAD_HALF(b0, 0)
  LOAD_HALF(b1, 1)

  if (t < 200) {                                    // 100 rows x 2 halves of 64ch
    const int row = t >> 1, half = t & 1;
    const int dh = row / 10, dw = row - dh * 10;
    const int h = h0 + dh - 1, w = w0 + dw - 1;
    unsigned short* ld = &patch[row * 136 + half * 64];
    if (h >= 0 && h < HH && w >= 0 && w < WW) {
      const unsigned short* src = in + ((size_t)((b * HH + h) * WW + w)) * CH + half * 64;
      if (FUSE) {
        #pragma unroll
        for (int j = 0; j < 8; ++j) {
          const bfv8 v = *(const bfv8*)(src + j * 8);
          bfv8 o;
          #pragma unroll
          for (int k = 0; k < 8; ++k) {
            const int c = half * 64 + j * 8 + k;
            const float f = fmaxf(bf2f(v[k]) * tab[c] + tab[CH + c], 0.0f);
            o[k] = f2bf(f);
          }
          *(bfv8*)(ld + j * 8) = o;
        }
      } else {
        #pragma unroll
        for (int j = 0; j < 8; ++j)
          *(bfv8*)(ld + j * 8) = *(const bfv8*)(src + j * 8);
      }
    } else {
      const bfv8 z = {0, 0, 0, 0, 0, 0, 0, 0};
      #pragma unroll
      for (int j = 0; j < 8; ++j) *(bfv8*)(ld + j * 8) = z;
    }
  }
  __syncthreads();

  f32x4 acc[2][4];
  #pragma unroll
  for (int m = 0; m < 2; ++m)
    #pragma unroll
    for (int n = 0; n < 4; ++n) acc[m][n] = (f32x4){0.f, 0.f, 0.f, 0.f};

#define MFMA_HALF(src, I) { \
    const int posb_ = (pyl + ((I) / 2) / 3) * 10 + px + ((I) / 2) % 3; \
    _Pragma("unroll") \
    for (int c2 = 0; c2 < 2; ++c2) { \
      _Pragma("unroll") \
      for (int nf = 0; nf < 4; ++nf) { \
        const short8v bfr = \
            *(const short8v*)(&patch[(posb_ + nf * 20) * 136 + (((I) % 2) * 2 + c2) * 32 + lgrp * 8]); \
        acc[0][nf] = __builtin_amdgcn_mfma_f32_16x16x32_bf16(src[c2 * 2 + 0], bfr, acc[0][nf], 0, 0, 0); \
        acc[1][nf] = __builtin_amdgcn_mfma_f32_16x16x32_bf16(src[c2 * 2 + 1], bfr, acc[1][nf], 0, 0, 0); \
      } } }

  // 18 half-taps, depth-1 lookahead over 2 rotating buffers (WAR on the
  // buffer regs forces the reload to issue after the MFMAs that read it).
  MFMA_HALF(b0,  0) LOAD_HALF(b0,  2)
  MFMA_HALF(b1,  1) LOAD_HALF(b1,  3)
  MFMA_HALF(b0,  2) LOAD_HALF(b0,  4)
  MFMA_HALF(b1,  3) LOAD_HALF(b1,  5)
  MFMA_HALF(b0,  4) LOAD_HALF(b0,  6)
  MFMA_HALF(b1,  5) LOAD_HALF(b1,  7)
  MFMA_HALF(b0,  6) LOAD_HALF(b0,  8)
  MFMA_HALF(b1,  7) LOAD_HALF(b1,  9)
  MFMA_HALF(b0,  8) LOAD_HALF(b0, 10)
  MFMA_HALF(b1,  9) LOAD_HALF(b1, 11)
  MFMA_HALF(b0, 10) LOAD_HALF(b0, 12)
  MFMA_HALF(b1, 11) LOAD_HALF(b1, 13)
  MFMA_HALF(b0, 12) LOAD_HALF(b0, 14)
  MFMA_HALF(b1, 13) LOAD_HALF(b1, 15)
  MFMA_HALF(b0, 14) LOAD_HALF(b0, 16)
  MFMA_HALF(b1, 15) LOAD_HALF(b1, 17)
  MFMA_HALF(b0, 16)
  MFMA_HALF(b1, 17)
#undef LOAD_HALF
#undef MFMA_HALF

  __syncthreads();   // patch reads done everywhere; reuse patch as output buffer

  // Stage D into LDS: obuf[pixel p 0..63][ch 0..127] bf16, byte ^= ((p&3)<<5).
  char* obuf = (char*)patch;
  #pragma unroll
  for (int mf = 0; mf < 2; ++mf) {
    #pragma unroll
    for (int nf = 0; nf < 4; ++nf) {
      const f32x4 v = acc[mf][nf];
      bfv4 pk;
      #pragma unroll
      for (int r = 0; r < 4; ++r) pk[r] = f2bf(v[r]);
      const int p = (nf * 2 + pyl) * 8 + px;
      const int ch = wv * 32 + mf * 16 + lgrp * 4;
      int byte = p * 256 + ch * 2;
      byte ^= ((byte >> 8) & 3) << 5;
      *(bfv4*)(obuf + byte) = pk;
    }
  }

  // Fused BN stat partials: shuffle-reduce over the 16 pixel-col lanes,
  // LDS-accumulate, then ONE non-atomic 256-float row per block.
  #pragma unroll
  for (int mf = 0; mf < 2; ++mf) {
    f32x4 sv4 = {0.f, 0.f, 0.f, 0.f}, qv4 = {0.f, 0.f, 0.f, 0.f};
    #pragma unroll
    for (int nf = 0; nf < 4; ++nf) {
      const f32x4 v = acc[mf][nf];
      sv4 += v;
      qv4 += v * v;
    }
    #pragma unroll
    for (int r = 0; r < 4; ++r) {
      float sv = sv4[r], qv = qv4[r];
      sv += __shfl_xor(sv, 1, 64);  qv += __shfl_xor(qv, 1, 64);
      sv += __shfl_xor(sv, 2, 64);  qv += __shfl_xor(qv, 2, 64);
      sv += __shfl_xor(sv, 4, 64);  qv += __shfl_xor(qv, 4, 64);
      sv += __shfl_xor(sv, 8, 64);  qv += __shfl_xor(qv, 8, 64);
      if (lrow == 0) {
        const int ch = wv * 32 + mf * 16 + lgrp * 4 + r;
        atomicAdd(&sacc[ch], sv);        // LDS atomic, 8 per thread-group
        atomicAdd(&sacc[CH + ch], qv);
      }
    }
  }

  __syncthreads();

  partials[(size_t)blockIdx.x * 256 + t] = sacc[t];

  // Copy out: 4 passes x 256 threads x 16B, contiguous 1KB per wave.
  #pragma unroll
  for (int j = 0; j < 4; ++j) {
    const int u = j * 256 + t;           // 16B unit index, 0..1023
    int byte = u * 16;
    byte ^= ((byte >> 8) & 3) << 5;
    const bfv8 v = *(const bfv8*)(obuf + byte);
    const int pix = u >> 4, py = pix >> 3, pxx = pix & 7;
    *(bfv8*)(outp + ((size_t)((b * HH + h0 + py) * WW + (w0 + pxx))) * CH +
             (u & 15) * 8) = v;
  }
}

// ---------------------------------------------------------------------------
// K-red: reduce partials[3136][256] -> st[256]. 32 blocks x 256 thr.
__global__ __launch_bounds__(256)
void stat_reduce(const float* __restrict__ partials, float* __restrict__ st) {
  const int t = threadIdx.x;
  float s = 0.0f;
  const int i0 = blockIdx.x * (NCONVBLK / 32);
  for (int i = 0; i < NCONVBLK / 32; ++i)
    s += partials[(size_t)(i0 + i) * 256 + t];
  atomicAdd(&st[t], s);
}

// ---------------------------------------------------------------------------
// K4/K6: per-channel BN stats -> scale/shift tables.
__global__ __launch_bounds__(128)
void bn_stats(const float* __restrict__ st, const float* __restrict__ gamma,
              const float* __restrict__ beta, float* __restrict__ tab) {
  const int c = threadIdx.x;
  const float inv = 1.0f / NPIXF;
  const float mean = st[c] * inv;
  const float var = st[CH + c] * inv - mean * mean;
  const float s = gamma[c] / sqrtf(var + 1e-5f);
  tab[c] = s;
  tab[CH + c] = beta[c] - mean * s;
}

// ---------------------------------------------------------------------------
// K7: out = relu(scale2*y2 + shift2 + residual), NHWC bf16 -> NCHW fp32.
// BF16RES: residual from xT (bf16 NHWC, 51MB) instead of x (fp32 NCHW, 205MB).
template<bool BF16RES>
__global__ __launch_bounds__(256)
void final_kernel(const unsigned short* __restrict__ y2,
                  const unsigned short* __restrict__ xbf,
                  const float* __restrict__ x,
                  const float* __restrict__ tab, float* __restrict__ out) {
  const int bid = blockIdx.x;
  const int b = bid / 14, hq = bid % 14;
  const int h = hq * 4 + (threadIdx.x >> 6);
  const int w = threadIdx.x & 63;
  if (w >= WW) return;
  const unsigned short* ys = y2 + ((size_t)(b * HH + h) * WW + w) * CH;
  const unsigned short* rs = xbf + ((size_t)(b * HH + h) * WW + w) * CH;
  const float* xs = x + (size_t)b * CH * HWPIX + h * WW + w;
  float* os = out + (size_t)b * CH * HWPIX + h * WW + w;
  #pragma unroll 4
  for (int c = 0; c < CH; ++c) {
    const float v = bf2f(ys[c]);
    const float res = BF16RES ? bf2f(rs[c]) : xs[(size_t)c * HWPIX];
    const float r = v * tab[c] + tab[CH + c] + res;
    os[(size_t)c * HWPIX] = fmaxf(r, 0.0f);
  }
}

// ---------------------------------------------------------------------------
extern "C" void kernel_launch(void* const* d_in, const int* in_sizes, int n_in,
                              void* d_out, int out_size, void* d_ws, size_t ws_size,
                              hipStream_t stream) {
  const float* x  = (const float*)d_in[0];
  const float* w1 = (const float*)d_in[1];
  const float* w2 = (const float*)d_in[2];
  const float* g1 = (const float*)d_in[3];
  const float* b1 = (const float*)d_in[4];
  const float* g2 = (const float*)d_in[5];
  const float* b2 = (const float*)d_in[6];
  float* out = (float*)d_out;

  // Workspace layout (bytes):
  //   xT   0            51,380,224
  //   y1   51,380,224   51,380,224
  //   w1b  102,760,448  18,874,368
  //   w2b  121,634,816  18,874,368
  //   p1   140,509,184  3,211,264
  //   p2   143,720,448  3,211,264
  //   st   146,931,712  4,096   (st1|st2|tab1|tab2, 256 floats each)
  //   y2   146,935,808  51,380,224  (optional, if ws_size allows)
  char* ws = (char*)d_ws;
  unsigned short* xT  = (unsigned short*)(ws);
  unsigned short* y1  = (unsigned short*)(ws + 51380224);
  unsigned short* w1b = (unsigned short*)(ws + 102760448);
  unsigned short* w2b = (unsigned short*)(ws + 121634816);
  float*          p1  = (float*)(ws + 140509184);
  float*          p2  = (float*)(ws + 143720448);
  float*          st  = (float*)(ws + 146931712);
  const bool sepY2 = ws_size >= (size_t)146935808 + 51380224;
  unsigned short* y2  = sepY2 ? (unsigned short*)(ws + 146935808) : xT;

  (void)hipMemsetAsync(st, 0, 2048, stream);  // zero st1+st2

  hipLaunchKernelGGL(prep_x, dim3(NB * 14), dim3(256), 0, stream, x, xT);
  hipLaunchKernelGGL(prep_w, dim3(1024), dim3(256), 0, stream, w1, w2, w1b, w2b);
  hipLaunchKernelGGL((conv_kernel<false>), dim3(NCONVBLK), dim3(256), 0, stream,
                     xT, w1b, y1, p1, (const float*)nullptr);
  hipLaunchKernelGGL(stat_reduce, dim3(32), dim3(256), 0, stream, p1, st);
  hipLaunchKernelGGL(bn_stats, dim3(1), dim3(128), 0, stream, st, g1, b1, st + 512);
  hipLaunchKernelGGL((conv_kernel<true>), dim3(NCONVBLK), dim3(256), 0, stream,
                     y1, w2b, y2, p2, st + 512);
  hipLaunchKernelGGL(stat_reduce, dim3(32), dim3(256), 0, stream, p2, st + 256);
  hipLaunchKernelGGL(bn_stats, dim3(1), dim3(128), 0, stream, st + 256, g2, b2, st + 768);
  if (sepY2) {
    hipLaunchKernelGGL((final_kernel<true>), dim3(NB * 14), dim3(256), 0, stream,
                       y2, xT, x, st + 768, out);
  } else {
    hipLaunchKernelGGL((final_kernel<false>), dim3(NB * 14), dim3(256), 0, stream,
                       y2, xT, x, st + 768, out);
  }
}